// Round 2
// baseline (50.550 us; speedup 1.0000x reference)
//
#include <hip/hip_runtime.h>
#include <hip/hip_bf16.h>

// out = leaky( rowscale(adj) @ X @ W^T + b ),  B=16, N=1024, F_IN=F_OUT=128
// Reassociated: Y = X @ W^T  (kernel 1, writes Y^T bf16 to ws)
//               out = invdeg * (adj @ Y) + b, leaky  (kernel 2, LDS-free K-loop)

typedef __attribute__((ext_vector_type(8))) __bf16 bf16x8;
typedef __attribute__((ext_vector_type(4))) float f32x4;

// round-to-nearest-even fp32 -> bf16 (finite inputs), packed pair into u32
__device__ __forceinline__ unsigned f2bf_pk(float lo, float hi) {
    union { float f; unsigned u; } a, b;
    a.f = lo; b.f = hi;
    unsigned ra = (a.u + 0x7FFFu + ((a.u >> 16) & 1u)) >> 16;
    unsigned rb = (b.u + 0x7FFFu + ((b.u >> 16) & 1u)) & 0xFFFF0000u;
    return ra | rb;
}

__device__ __forceinline__ bf16x8 cvt8(const f32x4& a, const f32x4& b) {
    union { unsigned u[4]; bf16x8 v; } r;
    r.u[0] = f2bf_pk(a.x, a.y);
    r.u[1] = f2bf_pk(a.z, a.w);
    r.u[2] = f2bf_pk(b.x, b.y);
    r.u[3] = f2bf_pk(b.z, b.w);
    return r.v;
}

// ---------------- Kernel 1: Y^T[b][o][m] = sum_f X[b][m][f] * W[o][f] ----------------
// grid 512 (16 batches x 32 row-blocks of 32), block 256 (4 waves, 2x2 wave tiles 16x64)
__global__ __launch_bounds__(256, 2)
void k1_xw(const float* __restrict__ x, const float* __restrict__ W,
           unsigned short* __restrict__ yT)
{
    __shared__ unsigned short Ax[32 * 128];   // X tile [m][f] bf16, rows 256B, swizzled
    __shared__ unsigned short Bw[128 * 128];  // W      [o][f] bf16, rows 256B, swizzled

    const int t  = threadIdx.x;
    const int wg = blockIdx.x;
    const int b  = wg >> 5;
    const int m0 = (wg & 31) << 5;
    const float* xb = x + (((long)b << 10) + m0) * 128;

#pragma unroll
    for (int i = 0; i < 4; ++i) {
        int e = i * 1024 + t * 4;
        int r = e >> 7, f = e & 127;
        f32x4 v = *(const f32x4*)(xb + (long)r * 128 + f);
        int c = f >> 3;
        int byte = r * 256 + (((c ^ (r & 7)) << 4) | ((f & 7) << 1));
        uint2 pk; pk.x = f2bf_pk(v.x, v.y); pk.y = f2bf_pk(v.z, v.w);
        *(uint2*)((char*)Ax + byte) = pk;
    }
#pragma unroll
    for (int i = 0; i < 16; ++i) {
        int e = i * 1024 + t * 4;
        int r = e >> 7, f = e & 127;
        f32x4 v = *(const f32x4*)(W + r * 128 + f);
        int c = f >> 3;
        int byte = r * 256 + (((c ^ (r & 7)) << 4) | ((f & 7) << 1));
        uint2 pk; pk.x = f2bf_pk(v.x, v.y); pk.y = f2bf_pk(v.z, v.w);
        *(uint2*)((char*)Bw + byte) = pk;
    }
    __syncthreads();

    const int lane = t & 63, w = t >> 6;
    const int wm = w >> 1, wn = w & 1;
    const int lrow = lane & 15, lq = lane >> 4;

    bf16x8 af[4];
#pragma unroll
    for (int kk = 0; kk < 4; ++kk) {
        int r = wm * 16 + lrow;
        int c = kk * 4 + lq;
        af[kk] = *(const bf16x8*)((const char*)Ax + r * 256 + ((c ^ (r & 7)) << 4));
    }

    f32x4 zero = {0.f, 0.f, 0.f, 0.f};
    f32x4 acc[4] = {zero, zero, zero, zero};
#pragma unroll
    for (int nf = 0; nf < 4; ++nf) {
#pragma unroll
        for (int kk = 0; kk < 4; ++kk) {
            int o = wn * 64 + nf * 16 + lrow;
            int c = kk * 4 + lq;
            bf16x8 bfrag = *(const bf16x8*)((const char*)Bw + o * 256 + ((c ^ (o & 7)) << 4));
            acc[nf] = __builtin_amdgcn_mfma_f32_16x16x32_bf16(af[kk], bfrag, acc[nf], 0, 0, 0);
        }
    }

#pragma unroll
    for (int nf = 0; nf < 4; ++nf) {
        int o  = wn * 64 + nf * 16 + lrow;
        int mb = m0 + wm * 16 + lq * 4;
        uint2 pk;
        pk.x = f2bf_pk(acc[nf][0], acc[nf][1]);
        pk.y = f2bf_pk(acc[nf][2], acc[nf][3]);
        *(uint2*)(yT + (((long)b * 128 + o) << 10) + mb) = pk;
    }
}

// ---------------- Kernel 2: out = leaky( invdeg * (adj @ Y) + bias ) ----------------
// LDS-free K-loop: MFMA fragments loaded directly from global (adj fp32 -> in-reg bf16,
// yT bf16 native). Each 16x128 tile is K-split across the block's 4 waves (K=256 each);
// single barrier + LDS reduction at the end. Grid 1024, XCD-bijective mapping so each
// XCD owns 2 batches -> that batch's yT slice (512KB) stays L2-resident.
__global__ __launch_bounds__(256, 4)
void k2_agg(const float* __restrict__ adj, const unsigned short* __restrict__ yT,
            const float* __restrict__ bias, float* __restrict__ out)
{
    __shared__ float accbuf[4][16 * 132];   // 33792 B, 132-stride: 16B-aligned rows
    __shared__ float degw[4][16];

    const int bid = blockIdx.x;
    const int xcd = bid & 7;
    const int j   = bid >> 3;             // 0..127
    const int b   = xcd * 2 + (j >> 6);   // each XCD: 2 batches
    const int n0  = (j & 63) << 4;

    const int t = threadIdx.x;
    const int lane = t & 63, w = t >> 6;
    const int lrow = lane & 15, lq = lane >> 4;

    const float* adjr = adj + ((long)(b * 1024 + n0 + lrow)) * 1024 + lq * 8;
    const unsigned short* yTr = yT + ((long)b << 17) + lq * 8;

    f32x4 zero = {0.f, 0.f, 0.f, 0.f};
    f32x4 acc[8] = {zero, zero, zero, zero, zero, zero, zero, zero};
    float dsum = 0.f;

    const int kbase = w << 8;   // this wave's K-quarter
#pragma unroll 2
    for (int kk = 0; kk < 8; ++kk) {
        const int k0 = kbase + kk * 32;
        f32x4 v0 = *(const f32x4*)(adjr + k0);
        f32x4 v1 = *(const f32x4*)(adjr + k0 + 4);
        dsum += v0.x + v0.y + v0.z + v0.w + v1.x + v1.y + v1.z + v1.w;
        bf16x8 a = cvt8(v0, v1);
#pragma unroll
        for (int ot = 0; ot < 8; ++ot) {
            bf16x8 bb = *(const bf16x8*)(yTr + (((long)(ot * 16 + lrow)) << 10) + k0);
            acc[ot] = __builtin_amdgcn_mfma_f32_16x16x32_bf16(a, bb, acc[ot], 0, 0, 0);
        }
    }

    // per-row degree partial: reduce across the 4 lq-groups sharing lrow
    dsum += __shfl_xor(dsum, 16, 64);
    dsum += __shfl_xor(dsum, 32, 64);
    if (lq == 0) degw[w][lrow] = dsum;

    // dump accumulators for cross-wave (K-quarter) reduction
#pragma unroll
    for (int ot = 0; ot < 8; ++ot)
#pragma unroll
        for (int i = 0; i < 4; ++i)
            accbuf[w][(lq * 4 + i) * 132 + ot * 16 + lrow] = acc[ot][i];
    __syncthreads();

    // epilogue: thread t -> row n = t>>4, cols o0..o0+7
    {
        const int n = t >> 4, o0 = (t & 15) * 8;
        float deg = degw[0][n] + degw[1][n] + degw[2][n] + degw[3][n];
        float inv = 1.0f / deg;
        f32x4 s0 = zero, s1 = zero;
#pragma unroll
        for (int ww = 0; ww < 4; ++ww) {
            s0 += *(const f32x4*)&accbuf[ww][n * 132 + o0];
            s1 += *(const f32x4*)&accbuf[ww][n * 132 + o0 + 4];
        }
        f32x4 b0 = *(const f32x4*)(bias + o0);
        f32x4 b1 = *(const f32x4*)(bias + o0 + 4);
        f32x4 r0, r1;
#pragma unroll
        for (int i = 0; i < 4; ++i) {
            float v = s0[i] * inv + b0[i];
            r0[i] = (v >= 0.f) ? v : 0.01f * v;
            float u = s1[i] * inv + b1[i];
            r1[i] = (u >= 0.f) ? u : 0.01f * u;
        }
        float* op = out + (((long)(b * 1024 + n0 + n)) << 7) + o0;
        *(f32x4*)op = r0;
        *(f32x4*)(op + 4) = r1;
    }
}

extern "C" void kernel_launch(void* const* d_in, const int* in_sizes, int n_in,
                              void* d_out, int out_size, void* d_ws, size_t ws_size,
                              hipStream_t stream) {
    const float* node = (const float*)d_in[0];   // [16,1024,128]
    const float* adj  = (const float*)d_in[1];   // [16,1024,1024]
    const float* W    = (const float*)d_in[2];   // [128,128]
    const float* bias = (const float*)d_in[3];   // [128]
    float* out = (float*)d_out;                  // [16,1024,128]
    unsigned short* yT = (unsigned short*)d_ws;  // 16*128*1024 bf16 = 4 MB scratch

    k1_xw<<<dim3(512), dim3(256), 0, stream>>>(node, W, yT);
    k2_agg<<<dim3(1024), dim3(256), 0, stream>>>(adj, yT, bias, out);
}

// Round 3
// 31.781 us; speedup vs baseline: 1.5905x; 1.5905x over previous
//
#include <hip/hip_runtime.h>
#include <hip/hip_bf16.h>

// out = leaky( rowscale(adj) @ X @ W^T + b ),  B=16, N=1024, F_IN=F_OUT=128
// Reassociated: Y = X @ W^T  (kernel 1, writes Y in MFMA-B-fragment layout to ws)
//               out = invdeg * (adj @ Y) + b, leaky  (kernel 2, LDS-free K-loop)
//
// yT fragment layout (ws): for batch b, k-step ks (32 m-values), o-tile ot (16 o):
//   element offset = ((b*32 + ks)*8 + ot)*1024 + lane*8 + j,  j=0..7
//   holding Y[m = ks*32 + (lane>>4)*8 + j][o = ot*16 + (lane&15)]
// so k2's B-fragment load is base + lane*16B  -> fully coalesced (no TA scatter).

typedef __attribute__((ext_vector_type(8))) __bf16 bf16x8;
typedef __attribute__((ext_vector_type(4))) float f32x4;

// round-to-nearest-even fp32 -> bf16 (finite inputs), packed pair into u32
__device__ __forceinline__ unsigned f2bf_pk(float lo, float hi) {
    union { float f; unsigned u; } a, b;
    a.f = lo; b.f = hi;
    unsigned ra = (a.u + 0x7FFFu + ((a.u >> 16) & 1u)) >> 16;
    unsigned rb = (b.u + 0x7FFFu + ((b.u >> 16) & 1u)) & 0xFFFF0000u;
    return ra | rb;
}

__device__ __forceinline__ bf16x8 cvt8(const f32x4& a, const f32x4& b) {
    union { unsigned u[4]; bf16x8 v; } r;
    r.u[0] = f2bf_pk(a.x, a.y);
    r.u[1] = f2bf_pk(a.z, a.w);
    r.u[2] = f2bf_pk(b.x, b.y);
    r.u[3] = f2bf_pk(b.z, b.w);
    return r.v;
}

// ---------------- Kernel 1: Y = X @ W^T, stored in fragment layout ----------------
// grid 512 (16 batches x 32 row-blocks of 32), block 256 (4 waves, 2x2 wave tiles 16x64)
__global__ __launch_bounds__(256, 2)
void k1_xw(const float* __restrict__ x, const float* __restrict__ W,
           unsigned short* __restrict__ yF)
{
    __shared__ unsigned short Ax[32 * 128];   // X tile [m][f] bf16, rows 256B, swizzled
    __shared__ unsigned short Bw[128 * 128];  // W      [o][f] bf16, rows 256B, swizzled

    const int t  = threadIdx.x;
    const int wg = blockIdx.x;
    const int b  = wg >> 5;
    const int m0 = (wg & 31) << 5;
    const float* xb = x + (((long)b << 10) + m0) * 128;

#pragma unroll
    for (int i = 0; i < 4; ++i) {
        int e = i * 1024 + t * 4;
        int r = e >> 7, f = e & 127;
        f32x4 v = *(const f32x4*)(xb + (long)r * 128 + f);
        int c = f >> 3;
        int byte = r * 256 + (((c ^ (r & 7)) << 4) | ((f & 7) << 1));
        uint2 pk; pk.x = f2bf_pk(v.x, v.y); pk.y = f2bf_pk(v.z, v.w);
        *(uint2*)((char*)Ax + byte) = pk;
    }
#pragma unroll
    for (int i = 0; i < 16; ++i) {
        int e = i * 1024 + t * 4;
        int r = e >> 7, f = e & 127;
        f32x4 v = *(const f32x4*)(W + r * 128 + f);
        int c = f >> 3;
        int byte = r * 256 + (((c ^ (r & 7)) << 4) | ((f & 7) << 1));
        uint2 pk; pk.x = f2bf_pk(v.x, v.y); pk.y = f2bf_pk(v.z, v.w);
        *(uint2*)((char*)Bw + byte) = pk;
    }
    __syncthreads();

    const int lane = t & 63, w = t >> 6;
    const int wm = w >> 1, wn = w & 1;
    const int lrow = lane & 15, lq = lane >> 4;

    bf16x8 af[4];
#pragma unroll
    for (int kk = 0; kk < 4; ++kk) {
        int r = wm * 16 + lrow;
        int c = kk * 4 + lq;
        af[kk] = *(const bf16x8*)((const char*)Ax + r * 256 + ((c ^ (r & 7)) << 4));
    }

    f32x4 zero = {0.f, 0.f, 0.f, 0.f};
    f32x4 acc[4] = {zero, zero, zero, zero};
#pragma unroll
    for (int nf = 0; nf < 4; ++nf) {
#pragma unroll
        for (int kk = 0; kk < 4; ++kk) {
            int o = wn * 64 + nf * 16 + lrow;
            int c = kk * 4 + lq;
            bf16x8 bfrag = *(const bf16x8*)((const char*)Bw + o * 256 + ((c ^ (o & 7)) << 4));
            acc[nf] = __builtin_amdgcn_mfma_f32_16x16x32_bf16(af[kk], bfrag, acc[nf], 0, 0, 0);
        }
    }

    // scatter into fragment layout:
    // this lane holds Y[m = m0 + wm*16 + lq*4 + i][o = wn*64 + nf*16 + lrow]
    //   ks = m0>>5 (constant for block), q = wm*2 + (lq>>1), jbase = (lq&1)*4
    //   ot = wn*4 + nf, r = lrow
    {
        const int ks = m0 >> 5;
        const int q  = wm * 2 + (lq >> 1);
        const int jb = (lq & 1) * 4;
#pragma unroll
        for (int nf = 0; nf < 4; ++nf) {
            int ot = wn * 4 + nf;
            uint2 pk;
            pk.x = f2bf_pk(acc[nf][0], acc[nf][1]);
            pk.y = f2bf_pk(acc[nf][2], acc[nf][3]);
            long off = (((long)(b * 32 + ks) * 8 + ot) << 10) + (q * 16 + lrow) * 8 + jb;
            *(uint2*)(yF + off) = pk;
        }
    }
}

// ---------------- Kernel 2: out = leaky( invdeg * (adj @ Y) + bias ) ----------------
// LDS-free K-loop. adj fragments loaded scattered (unavoidable for an input) with
// in-reg bf16 convert; Y fragments loaded COALESCED from the fragment-layout buffer.
// Each 16x128 tile K-split across 4 waves (K=256 each); one barrier + LDS reduce.
// Grid 1024, XCD-bijective: each XCD owns 2 batches (yF slice L2-resident).
__global__ __launch_bounds__(256, 4)
void k2_agg(const float* __restrict__ adj, const unsigned short* __restrict__ yF,
            const float* __restrict__ bias, float* __restrict__ out)
{
    __shared__ float accbuf[4][16 * 132];   // 33792 B
    __shared__ float degw[4][16];

    const int bid = blockIdx.x;
    const int xcd = bid & 7;
    const int j   = bid >> 3;             // 0..127
    const int b   = xcd * 2 + (j >> 6);   // each XCD: 2 batches
    const int n0  = (j & 63) << 4;

    const int t = threadIdx.x;
    const int lane = t & 63, w = t >> 6;
    const int lrow = lane & 15, lq = lane >> 4;

    const float* adjr = adj + ((long)(b * 1024 + n0 + lrow)) * 1024 + lq * 8;
    // this wave's K-quarter: ks = w*8 + kk; fragment base for (ks, ot=0), this lane
    const unsigned short* fr = yF + (((long)(b * 32 + w * 8) * 8) << 10) + lane * 8;

    f32x4 zero = {0.f, 0.f, 0.f, 0.f};
    f32x4 acc[8] = {zero, zero, zero, zero, zero, zero, zero, zero};
    float dsum = 0.f;

    const int kbase = w << 8;
    f32x4 v0 = *(const f32x4*)(adjr + kbase);
    f32x4 v1 = *(const f32x4*)(adjr + kbase + 4);
#pragma unroll
    for (int kk = 0; kk < 8; ++kk) {
        // coalesced Y fragment loads: lane*16B within each 2KB fragment
        bf16x8 bb[8];
#pragma unroll
        for (int ot = 0; ot < 8; ++ot)
            bb[ot] = *(const bf16x8*)(fr + ((kk * 8 + ot) << 10));

        // prefetch next adj chunk
        f32x4 n0v = zero, n1v = zero;
        if (kk < 7) {
            n0v = *(const f32x4*)(adjr + kbase + (kk + 1) * 32);
            n1v = *(const f32x4*)(adjr + kbase + (kk + 1) * 32 + 4);
        }

        dsum += v0.x + v0.y + v0.z + v0.w + v1.x + v1.y + v1.z + v1.w;
        bf16x8 a = cvt8(v0, v1);
#pragma unroll
        for (int ot = 0; ot < 8; ++ot)
            acc[ot] = __builtin_amdgcn_mfma_f32_16x16x32_bf16(a, bb[ot], acc[ot], 0, 0, 0);

        v0 = n0v; v1 = n1v;
    }

    // per-row degree partial: reduce across the 4 lq-groups sharing lrow
    dsum += __shfl_xor(dsum, 16, 64);
    dsum += __shfl_xor(dsum, 32, 64);
    if (lq == 0) degw[w][lrow] = dsum;

    // dump accumulators for cross-wave (K-quarter) reduction
#pragma unroll
    for (int ot = 0; ot < 8; ++ot)
#pragma unroll
        for (int i = 0; i < 4; ++i)
            accbuf[w][(lq * 4 + i) * 132 + ot * 16 + lrow] = acc[ot][i];
    __syncthreads();

    // epilogue: thread t -> row n = t>>4, cols o0..o0+7
    {
        const int n = t >> 4, o0 = (t & 15) * 8;
        float deg = degw[0][n] + degw[1][n] + degw[2][n] + degw[3][n];
        float inv = 1.0f / deg;
        f32x4 s0 = zero, s1 = zero;
#pragma unroll
        for (int ww = 0; ww < 4; ++ww) {
            s0 += *(const f32x4*)&accbuf[ww][n * 132 + o0];
            s1 += *(const f32x4*)&accbuf[ww][n * 132 + o0 + 4];
        }
        f32x4 b0 = *(const f32x4*)(bias + o0);
        f32x4 b1 = *(const f32x4*)(bias + o0 + 4);
        f32x4 r0, r1;
#pragma unroll
        for (int i = 0; i < 4; ++i) {
            float v = s0[i] * inv + b0[i];
            r0[i] = (v >= 0.f) ? v : 0.01f * v;
            float u = s1[i] * inv + b1[i];
            r1[i] = (u >= 0.f) ? u : 0.01f * u;
        }
        float* op = out + (((long)(b * 1024 + n0 + n)) << 7) + o0;
        *(f32x4*)op = r0;
        *(f32x4*)(op + 4) = r1;
    }
}

extern "C" void kernel_launch(void* const* d_in, const int* in_sizes, int n_in,
                              void* d_out, int out_size, void* d_ws, size_t ws_size,
                              hipStream_t stream) {
    const float* node = (const float*)d_in[0];   // [16,1024,128]
    const float* adj  = (const float*)d_in[1];   // [16,1024,1024]
    const float* W    = (const float*)d_in[2];   // [128,128]
    const float* bias = (const float*)d_in[3];   // [128]
    float* out = (float*)d_out;                  // [16,1024,128]
    unsigned short* yF = (unsigned short*)d_ws;  // 16*32*8*1024 bf16 = 4 MB scratch

    k1_xw<<<dim3(512), dim3(256), 0, stream>>>(node, W, yF);
    k2_agg<<<dim3(1024), dim3(256), 0, stream>>>(adj, yF, bias, out);
}

// Round 4
// 27.872 us; speedup vs baseline: 1.8137x; 1.1403x over previous
//
#include <hip/hip_runtime.h>
#include <hip/hip_bf16.h>

// out = leaky( rowscale(adj) @ X @ W^T + b ),  B=16, N=1024, F_IN=F_OUT=128
// k1: Y = X @ W^T, written in MFMA-B-fragment layout (512-elem fragments).
// k2: 64-row blocks (grid 256 = 1/CU), 4 waves K-split, LDS-free K-loop,
//     cross-wave reduce in LDS at the end. Degrees fused into adj loads.
//
// yF fragment layout: fragment (b, ks, ot) at elem offset ((b*32+ks)*8+ot)*512,
//   lane l elems j=0..7 at +l*8+j hold Y[m = ks*32 + (l>>4)*8 + j][o = ot*16 + (l&15)]
//   -> k2 B-fragment load = base + lane*16B, fully coalesced.

typedef __attribute__((ext_vector_type(8))) __bf16 bf16x8;
typedef __attribute__((ext_vector_type(4))) float f32x4;

__device__ __forceinline__ unsigned f2bf_pk(float lo, float hi) {
    union { float f; unsigned u; } a, b;
    a.f = lo; b.f = hi;
    unsigned ra = (a.u + 0x7FFFu + ((a.u >> 16) & 1u)) >> 16;
    unsigned rb = (b.u + 0x7FFFu + ((b.u >> 16) & 1u)) & 0xFFFF0000u;
    return ra | rb;
}

__device__ __forceinline__ bf16x8 cvt8(const f32x4& a, const f32x4& b) {
    union { unsigned u[4]; bf16x8 v; } r;
    r.u[0] = f2bf_pk(a.x, a.y);
    r.u[1] = f2bf_pk(a.z, a.w);
    r.u[2] = f2bf_pk(b.x, b.y);
    r.u[3] = f2bf_pk(b.z, b.w);
    return r.v;
}

// ---------------- Kernel 1: Y = X @ W^T -> fragment layout ----------------
// grid 256 (16 batches x 16 row-blocks of 64), block 256 (4 waves, each 16 rows x 128 o)
__global__ __launch_bounds__(256, 2)
void k1_xw(const float* __restrict__ x, const float* __restrict__ W,
           unsigned short* __restrict__ yF)
{
    __shared__ unsigned short Ax[64 * 128];   // X tile [m][f] bf16, rows 256B, swizzled
    __shared__ unsigned short Bw[128 * 128];  // W      [o][f] bf16, rows 256B, swizzled

    const int t   = threadIdx.x;
    const int bid = blockIdx.x;
    const int xcd = bid & 7;
    const int j   = bid >> 3;
    const int b   = xcd * 2 + (j >> 4);
    const int m0  = (j & 15) << 6;
    const float* xb = x + (((long)b << 10) + m0) * 128;

#pragma unroll
    for (int i = 0; i < 8; ++i) {
        int e = i * 1024 + t * 4;
        int r = e >> 7, f = e & 127;
        f32x4 v = *(const f32x4*)(xb + (long)r * 128 + f);
        int c = f >> 3;
        int byte = r * 256 + (((c ^ (r & 7)) << 4) | ((f & 7) << 1));
        uint2 pk; pk.x = f2bf_pk(v.x, v.y); pk.y = f2bf_pk(v.z, v.w);
        *(uint2*)((char*)Ax + byte) = pk;
    }
#pragma unroll
    for (int i = 0; i < 16; ++i) {
        int e = i * 1024 + t * 4;
        int r = e >> 7, f = e & 127;
        f32x4 v = *(const f32x4*)(W + r * 128 + f);
        int c = f >> 3;
        int byte = r * 256 + (((c ^ (r & 7)) << 4) | ((f & 7) << 1));
        uint2 pk; pk.x = f2bf_pk(v.x, v.y); pk.y = f2bf_pk(v.z, v.w);
        *(uint2*)((char*)Bw + byte) = pk;
    }
    __syncthreads();

    const int lane = t & 63, w = t >> 6;
    const int lrow = lane & 15, lq = lane >> 4;

    bf16x8 af[4];
#pragma unroll
    for (int kk = 0; kk < 4; ++kk) {
        int r = w * 16 + lrow;
        int c = kk * 4 + lq;
        af[kk] = *(const bf16x8*)((const char*)Ax + r * 256 + ((c ^ (r & 7)) << 4));
    }

    f32x4 zero = {0.f, 0.f, 0.f, 0.f};
    f32x4 acc[8] = {zero, zero, zero, zero, zero, zero, zero, zero};
#pragma unroll
    for (int nf = 0; nf < 8; ++nf) {
#pragma unroll
        for (int kk = 0; kk < 4; ++kk) {
            int o = nf * 16 + lrow;
            int c = kk * 4 + lq;
            bf16x8 bfrag = *(const bf16x8*)((const char*)Bw + o * 256 + ((c ^ (o & 7)) << 4));
            acc[nf] = __builtin_amdgcn_mfma_f32_16x16x32_bf16(af[kk], bfrag, acc[nf], 0, 0, 0);
        }
    }

    // scatter into fragment layout:
    // lane holds Y[m = m0 + w*16 + lq*4 + i][o = nf*16 + lrow]
    {
        const int ks = (m0 >> 5) + (w >> 1);
        const int q  = (w & 1) * 2 + (lq >> 1);
        const int jb = (lq & 1) * 4;
#pragma unroll
        for (int nf = 0; nf < 8; ++nf) {
            uint2 pk;
            pk.x = f2bf_pk(acc[nf][0], acc[nf][1]);
            pk.y = f2bf_pk(acc[nf][2], acc[nf][3]);
            long off = (((long)((b * 32 + ks) * 8 + nf)) << 9) + (q * 16 + lrow) * 8 + jb;
            *(uint2*)(yF + off) = pk;
        }
    }
}

// ---------------- Kernel 2: out = leaky( invdeg * (adj @ Y) + bias ) ----------------
// grid 256 (1 block/CU), block 256 (4 waves). Wave w: K-range [w*256, w*256+256),
// 4 row-groups x 8 o-tiles accumulators (128 VGPR). LDS-free K-loop; one barrier;
// column-major accbuf (stride 68) cross-wave reduce + invdeg + bias + leaky epilogue.
__global__ __launch_bounds__(256, 1)
void k2_agg(const float* __restrict__ adj, const unsigned short* __restrict__ yF,
            const float* __restrict__ bias, float* __restrict__ out)
{
    __shared__ float accbuf[4][128 * 68];   // 4 x 34816 B = 139264 B
    __shared__ float degw[4][64];

    const int bid = blockIdx.x;
    const int xcd = bid & 7;
    const int j   = bid >> 3;             // 0..31
    const int b   = xcd * 2 + (j >> 4);   // each XCD: 2 batches
    const int n0  = (j & 15) << 6;        // 64-row tile

    const int t = threadIdx.x;
    const int lane = t & 63, w = t >> 6;
    const int lrow = lane & 15, lq = lane >> 4;

    const float* adjr = adj + ((long)(b * 1024 + n0 + lrow)) * 1024 + (w << 8) + lq * 8;
    const unsigned short* fr = yF + (((long)(b * 32 + w * 8) * 8) << 9) + lane * 8;

    f32x4 zero = {0.f, 0.f, 0.f, 0.f};
    f32x4 acc[4][8];
#pragma unroll
    for (int rg = 0; rg < 4; ++rg)
#pragma unroll
        for (int ot = 0; ot < 8; ++ot) acc[rg][ot] = zero;
    float ds[4] = {0.f, 0.f, 0.f, 0.f};

#pragma unroll 2
    for (int kk = 0; kk < 8; ++kk) {
        f32x4 v0[4], v1[4];
#pragma unroll
        for (int rg = 0; rg < 4; ++rg) {
            v0[rg] = *(const f32x4*)(adjr + rg * 16384 + kk * 32);
            v1[rg] = *(const f32x4*)(adjr + rg * 16384 + kk * 32 + 4);
        }
        bf16x8 bb[8];
#pragma unroll
        for (int ot = 0; ot < 8; ++ot)
            bb[ot] = *(const bf16x8*)(fr + ((kk * 8 + ot) << 9));

        bf16x8 a[4];
#pragma unroll
        for (int rg = 0; rg < 4; ++rg) {
            ds[rg] += v0[rg].x + v0[rg].y + v0[rg].z + v0[rg].w
                    + v1[rg].x + v1[rg].y + v1[rg].z + v1[rg].w;
            a[rg] = cvt8(v0[rg], v1[rg]);
        }
#pragma unroll
        for (int rg = 0; rg < 4; ++rg)
#pragma unroll
            for (int ot = 0; ot < 8; ++ot)
                acc[rg][ot] = __builtin_amdgcn_mfma_f32_16x16x32_bf16(a[rg], bb[ot], acc[rg][ot], 0, 0, 0);
    }

    // per-row degree partials: reduce over the 4 lq groups sharing lrow
#pragma unroll
    for (int rg = 0; rg < 4; ++rg) {
        float d = ds[rg];
        d += __shfl_xor(d, 16, 64);
        d += __shfl_xor(d, 32, 64);
        if (lq == 0) degw[w][rg * 16 + lrow] = d;
    }

    // dump accumulators, column-major [o][n] stride 68 (16B-aligned rows)
#pragma unroll
    for (int rg = 0; rg < 4; ++rg)
#pragma unroll
        for (int ot = 0; ot < 8; ++ot)
            *(f32x4*)&accbuf[w][(ot * 16 + lrow) * 68 + rg * 16 + lq * 4] = acc[rg][ot];
    __syncthreads();

    // epilogue: lane n = t&63 -> row n; wave w -> cols w*32 .. w*32+31
    {
        const int n = lane;
        const int o0 = w * 32;
        float deg = degw[0][n] + degw[1][n] + degw[2][n] + degw[3][n];
        float inv = 1.0f / deg;
        float res[32];
#pragma unroll
        for (int c = 0; c < 32; ++c) {
            float s = accbuf[0][(o0 + c) * 68 + n] + accbuf[1][(o0 + c) * 68 + n]
                    + accbuf[2][(o0 + c) * 68 + n] + accbuf[3][(o0 + c) * 68 + n];
            float v = s * inv + bias[o0 + c];
            res[c] = (v >= 0.f) ? v : 0.01f * v;
        }
        float* op = out + (((long)(b * 1024 + n0 + n)) << 7) + o0;
#pragma unroll
        for (int g = 0; g < 8; ++g) {
            f32x4 r = {res[g * 4], res[g * 4 + 1], res[g * 4 + 2], res[g * 4 + 3]};
            *(f32x4*)(op + g * 4) = r;
        }
    }
}

extern "C" void kernel_launch(void* const* d_in, const int* in_sizes, int n_in,
                              void* d_out, int out_size, void* d_ws, size_t ws_size,
                              hipStream_t stream) {
    const float* node = (const float*)d_in[0];   // [16,1024,128]
    const float* adj  = (const float*)d_in[1];   // [16,1024,1024]
    const float* W    = (const float*)d_in[2];   // [128,128]
    const float* bias = (const float*)d_in[3];   // [128]
    float* out = (float*)d_out;                  // [16,1024,128]
    unsigned short* yF = (unsigned short*)d_ws;  // 16*32*8*512 bf16 = 4 MB scratch

    k1_xw<<<dim3(256), dim3(256), 0, stream>>>(node, W, yF);
    k2_agg<<<dim3(256), dim3(256), 0, stream>>>(adj, yF, bias, out);
}